// Round 4
// baseline (2576.555 us; speedup 1.0000x reference)
//
#include <hip/hip_runtime.h>
#include <hip/hip_bf16.h>
#include <stdint.h>

#define NN 512
#define FEAT 128
#define EMBD 64
#define HID 128
#define WPB 4          // walks interleaved per wave

typedef float f32x4 __attribute__((ext_vector_type(4)));
typedef short s16x8 __attribute__((ext_vector_type(8)));

// ---------------- Threefry-2x32 (exact JAX semantics) ----------------
__device__ __forceinline__ uint32_t rotl32(uint32_t v, int s){ return (v << s) | (v >> (32 - s)); }

__device__ __forceinline__ void tf2x32(uint32_t k0, uint32_t k1, uint32_t x0, uint32_t x1,
                                       uint32_t &o0, uint32_t &o1){
  uint32_t k2 = k0 ^ k1 ^ 0x1BD11BDAu;
  x0 += k0; x1 += k1;
  x0+=x1; x1=rotl32(x1,13); x1^=x0;
  x0+=x1; x1=rotl32(x1,15); x1^=x0;
  x0+=x1; x1=rotl32(x1,26); x1^=x0;
  x0+=x1; x1=rotl32(x1, 6); x1^=x0;
  x0 += k1; x1 += k2 + 1u;
  x0+=x1; x1=rotl32(x1,17); x1^=x0;
  x0+=x1; x1=rotl32(x1,29); x1^=x0;
  x0+=x1; x1=rotl32(x1,16); x1^=x0;
  x0+=x1; x1=rotl32(x1,24); x1^=x0;
  x0 += k2; x1 += k0 + 2u;
  x0+=x1; x1=rotl32(x1,13); x1^=x0;
  x0+=x1; x1=rotl32(x1,15); x1^=x0;
  x0+=x1; x1=rotl32(x1,26); x1^=x0;
  x0+=x1; x1=rotl32(x1, 6); x1^=x0;
  x0 += k0; x1 += k1 + 3u;
  x0+=x1; x1=rotl32(x1,17); x1^=x0;
  x0+=x1; x1=rotl32(x1,29); x1^=x0;
  x0+=x1; x1=rotl32(x1,16); x1^=x0;
  x0+=x1; x1=rotl32(x1,24); x1^=x0;
  x0 += k1; x1 += k2 + 4u;
  x0+=x1; x1=rotl32(x1,13); x1^=x0;
  x0+=x1; x1=rotl32(x1,15); x1^=x0;
  x0+=x1; x1=rotl32(x1,26); x1^=x0;
  x0+=x1; x1=rotl32(x1, 6); x1^=x0;
  x0 += k2; x1 += k0 + 5u;
  o0 = x0; o1 = x1;
}

// uniform(key,(n,),0.01,0.1) bit-exact elementwise transform
__device__ __forceinline__ float bits_to_noise(uint32_t bits){
  float u = __builtin_bit_cast(float, (bits >> 9) | 0x3f800000u) - 1.0f;
  const float dlt = 0.1f - 0.01f;
  float v = __fadd_rn(__fmul_rn(u, dlt), 0.01f); // no FMA, as XLA emits
  return fmaxf(0.01f, v);
}

__device__ __forceinline__ short f2bf(float f){
  uint32_t u = __builtin_bit_cast(uint32_t, f);
  u += 0x7fffu + ((u >> 16) & 1u);
  return (short)(u >> 16);
}

__device__ __forceinline__ float fsig(float x){
  return __builtin_amdgcn_rcpf(1.0f + __expf(-x));
}
__device__ __forceinline__ float ftanh(float x){
  float e = __expf(2.0f * x);
  return 1.0f - 2.0f * __builtin_amdgcn_rcpf(e + 1.0f);
}
__device__ __forceinline__ float softplusf(float x){
  return log1pf(expf(x));
}

// ---------------- fast 64-lane reductions (DPP + swizzle) ----------------
__device__ __forceinline__ float wave_fmax(float x){
  int xi;
  #define DSTEP(C) xi = __builtin_amdgcn_update_dpp(0, __builtin_bit_cast(int,x), C, 0xF, 0xF, true); \
                   x = fmaxf(x, __builtin_bit_cast(float,xi));
  DSTEP(0xB1)   /* xor1  */
  DSTEP(0x4E)   /* xor2  */
  DSTEP(0x141)  /* xor4  row_half_mirror */
  DSTEP(0x140)  /* xor8  row_mirror      */
  #undef DSTEP
  xi = __builtin_amdgcn_ds_swizzle(__builtin_bit_cast(int,x), 0x401F); // xor16
  x = fmaxf(x, __builtin_bit_cast(float,xi));
  x = fmaxf(x, __shfl_xor(x, 32));
  return x;
}
__device__ __forceinline__ uint32_t wave_maxu(uint32_t x){
  int m;
  #define USTEP(C) m = __builtin_amdgcn_update_dpp(0, (int)x, C, 0xF, 0xF, true); \
                   x = x > (uint32_t)m ? x : (uint32_t)m;
  USTEP(0xB1) USTEP(0x4E) USTEP(0x141) USTEP(0x140)
  #undef USTEP
  m = __builtin_amdgcn_ds_swizzle((int)x, 0x401F);
  x = x > (uint32_t)m ? x : (uint32_t)m;
  uint32_t o = (uint32_t)__shfl_xor((int)x, 32);
  x = x > o ? x : o;
  return x;
}

// ---------------- one greedy-walk step (identical math to round 3) ----------------
__device__ __forceinline__ void walk_step(int t, int lane,
    const float* __restrict__ adj, int* __restrict__ orders, int s,
    uint32_t &vis, int &cur, float4 &r0, float4 &r1,
    const uint32_t* kts, float* ca, int* ci, unsigned long long lt){
  uint32_t kt0 = kts[2*t], kt1 = kts[2*t+1];
  float a[8] = {r0.x,r0.y,r0.z,r0.w,r1.x,r1.y,r1.z,r1.w};

  float mx = -1.f;
  #pragma unroll
  for (int e = 0; e < 8; ++e)
    mx = fmaxf(mx, ((vis >> e) & 1) ? -1.f : a[e]);
  mx = wave_fmax(mx);
  float T = mx - 0.0901f;

  int base = 0, pos[8]; uint32_t cm = 0;
  #pragma unroll
  for (int e = 0; e < 8; ++e){
    bool c = !((vis >> e) & 1) && (a[e] >= T);
    unsigned long long bal = __ballot(c);
    pos[e] = base + __popcll(bal & lt);
    base += __popcll(bal);
    if (c) cm |= 1u << e;
  }
  #pragma unroll
  for (int e = 0; e < 8; ++e)
    if ((cm >> e) & 1){ ca[pos[e]] = a[e]; ci[pos[e]] = lane*8 + e; }
  int total = base;

  uint32_t bk = 0; int bi = 0x7fffffff;
  for (int b0 = 0; b0 < total; b0 += 64){
    int k = b0 + lane;
    if (k < total){
      int idx = ci[k]; float av = ca[k];
      uint32_t x0, x1;
      tf2x32(kt0, kt1, 0u, (uint32_t)idx, x0, x1);
      float nz = bits_to_noise(x0 ^ x1);
      uint32_t a23 = (uint32_t)(av * 8388608.0f);      // *2^23 exact
      uint32_t n30 = (uint32_t)(nz * 1073741824.0f);   // *2^30 exact
      uint32_t key = (a23 << 7) + n30;
      if (key > bk || (key == bk && idx < bi)){ bk = key; bi = idx; }
    }
  }
  uint32_t km = wave_maxu(bk);
  unsigned long long msk = __ballot(bk == km);
  int widx;
  if (__popcll(msk) == 1){
    widx = __shfl(bi, __ffsll((long long)msk) - 1);
  } else {                                // rare exact-tie path
    int iv = (bk == km) ? bi : 0x7fffffff;
    #pragma unroll
    for (int off = 1; off < 64; off <<= 1){
      int o = __shfl_xor(iv, off);
      iv = o < iv ? o : iv;
    }
    widx = iv;
  }
  cur = widx;
  // issue next-row load immediately: hidden under the other walks' compute
  const float4* nr = (const float4*)(adj + (size_t)widx*NN);
  r0 = nr[lane*2]; r1 = nr[lane*2+1];
  if ((widx >> 3) == lane) vis |= 1u << (widx & 7);
  if (lane == 0) orders[(size_t)s*NN + t + 1] = widx;
}

// ---------------- mega-kernel body A: 4 interleaved walks per wave ----------------
__device__ __forceinline__ void orders_quad(const float* __restrict__ adj,
                                            int* __restrict__ orders, int bid){
  int lane = threadIdx.x;
  __shared__ uint32_t kts[WPB][2*(NN-1)];   // 16.0 KB
  __shared__ float ca[WPB][NN];             // 8 KB
  __shared__ int   ci[WPB][NN];             // 8 KB
  int s0 = bid*WPB;

  uint32_t ks[WPB][2];
  #pragma unroll
  for (int w = 0; w < WPB; ++w)
    tf2x32(0u, 42u, 0u, (uint32_t)(s0+w), ks[w][0], ks[w][1]);
  for (int t = lane; t < NN-1; t += 64){
    #pragma unroll
    for (int w = 0; w < WPB; ++w){
      uint32_t a, b; tf2x32(ks[w][0], ks[w][1], 0u, (uint32_t)t, a, b);
      kts[w][2*t] = a; kts[w][2*t+1] = b;
    }
  }
  // single wave: LDS same-wave RAW is ordered, no barrier needed

  uint32_t vis[WPB]; int cur[WPB]; float4 r0[WPB], r1[WPB];
  unsigned long long lt = (1ull << lane) - 1ull;
  #pragma unroll
  for (int w = 0; w < WPB; ++w){
    int s = s0 + w;
    vis[w] = ((s >> 3) == lane) ? (1u << (s & 7)) : 0u;
    cur[w] = s;
    if (lane == 0) orders[(size_t)s*NN] = s;
    const float4* r4 = (const float4*)(adj + (size_t)s*NN);
    r0[w] = r4[lane*2]; r1[w] = r4[lane*2+1];
  }

  for (int t = 0; t < NN-1; ++t){
    #pragma unroll
    for (int w = 0; w < WPB; ++w)
      walk_step(t, lane, adj, orders, s0+w, vis[w], cur[w], r0[w], r1[w],
                kts[w], ca[w], ci[w], lt);
  }
}

// ---------------- mega-kernel body B: fused input_feat + IFW ----------------
// neigh_feat = histogram(neighbor tags) @ W_emb  (dense 128-step GEMV)
__device__ __forceinline__ void featifw_body(int n, const int* __restrict__ tags,
    const float* __restrict__ adj, const float* __restrict__ W_emb,
    const float* __restrict__ b_emb, const float* __restrict__ W_ih,
    const float* __restrict__ b_ih, const float* __restrict__ b_hh,
    float* __restrict__ IFW){
  int tid = threadIdx.x;                 // = embedding dim d (0..63)
  __shared__ int tg[NN];
  __shared__ float cnt[FEAT];
  __shared__ __align__(16) float xs[2*EMBD];
  for (int i = tid; i < NN; i += 64) tg[i] = tags[i];
  cnt[tid] = 0.f; cnt[tid + 64] = 0.f;
  __syncthreads();
  const float* row = adj + (size_t)n*NN;
  #pragma unroll
  for (int c = 0; c < 8; ++c){
    float v = row[c*64 + tid];
    if (v > 0.5f) atomicAdd(&cnt[tg[c*64 + tid]], 1.0f);
  }
  __syncthreads();
  float acc = 0.f;
  #pragma unroll 16
  for (int k = 0; k < FEAT; ++k)
    acc = fmaf(cnt[k], W_emb[k*EMBD + tid], acc);
  xs[tid]        = W_emb[tg[n]*EMBD + tid] + b_emb[tid];
  xs[EMBD + tid] = acc + b_emb[tid];
  __syncthreads();
  const float4* xs4 = (const float4*)xs;
  for (int it = 0; it < 8; ++it){
    int g = it*64 + tid;
    const float4* wr4 = (const float4*)(W_ih + (size_t)g*(2*EMBD));
    float a2 = b_ih[g] + b_hh[g];
    #pragma unroll 8
    for (int kk = 0; kk < 32; ++kk){
      float4 wv = wr4[kk], xv = xs4[kk];
      a2 += wv.x*xv.x + wv.y*xv.y + wv.z*xv.z + wv.w*xv.w;
    }
    IFW[(size_t)n*(4*HID) + g] = a2;
  }
}

__global__ __launch_bounds__(64) void k_mega1(const float* __restrict__ adj,
    int* __restrict__ orders, const int* __restrict__ tags,
    const float* __restrict__ W_emb, const float* __restrict__ b_emb,
    const float* __restrict__ W_ih, const float* __restrict__ b_ih,
    const float* __restrict__ b_hh, float* __restrict__ IFW){
  if (blockIdx.x < NN/WPB) orders_quad(adj, orders, blockIdx.x);
  else                     featifw_body(blockIdx.x - NN/WPB, tags, adj, W_emb,
                                        b_emb, W_ih, b_ih, b_hh, IFW);
}

// ---------------- K2: persistent LSTM (8 waves) + fused MLP heads ----------------
__device__ __forceinline__ void lstm_step(int t, int w, int l15, int l4,
    const short (*hread)[HID+8], short (*hwrite)[HID+8],
    float (&vIFc)[4][4], float (&vIFn)[4][4],
    const s16x8 (&Bf)[4][4], float (&c)[4], float (&emb)[4],
    const int* ord_s, const float* __restrict__ IFW){
  int tn = (t + 1 < NN) ? t + 1 : NN - 1;
  #pragma unroll
  for (int r = 0; r < 4; ++r){
    int ord = ord_s[(l4*4 + r)*NN + tn];
    const float* base = IFW + (size_t)ord*(4*HID) + w*16 + l15;
    #pragma unroll
    for (int q = 0; q < 4; ++q) vIFn[q][r] = base[q*HID];
  }
  s16x8 Af[4];
  #pragma unroll
  for (int kt = 0; kt < 4; ++kt)
    Af[kt] = *(const s16x8*)&hread[l15][kt*32 + l4*8];
  f32x4 acc[4];
  #pragma unroll
  for (int q = 0; q < 4; ++q){
    f32x4 a = {vIFc[q][0], vIFc[q][1], vIFc[q][2], vIFc[q][3]};
    #pragma unroll
    for (int kt = 0; kt < 4; ++kt)
      a = __builtin_amdgcn_mfma_f32_16x16x32_bf16(Af[kt], Bf[q][kt], a, 0, 0, 0);
    acc[q] = a;
  }
  int col = w*16 + l15;
  #pragma unroll
  for (int r = 0; r < 4; ++r){
    float si = fsig(acc[0][r]);
    float sf = fsig(acc[1][r]);
    float tg = ftanh(acc[2][r]);
    float so = fsig(acc[3][r]);
    float cn = sf * c[r] + si * tg;
    c[r] = cn;
    float h = so * ftanh(cn);
    emb[r] += h;
    hwrite[l4*4 + r][col] = f2bf(h);
  }
  __syncthreads();
}

__global__ __launch_bounds__(512, 2) void k_lstm(const float* __restrict__ W_hh,
    const float* __restrict__ IFW, const int* __restrict__ orders,
    const float* __restrict__ W1s, const float* __restrict__ b1s,
    const float* __restrict__ W2s, const float* __restrict__ b2s,
    float* __restrict__ logits){
  int wg = blockIdx.x, tid = threadIdx.x;
  int w = tid >> 6, l = tid & 63, l15 = l & 15, l4 = l >> 4;
  __shared__ int ord_s[16*NN];
  __shared__ __align__(16) short hbuf[2][16][HID+8];
  __shared__ float part[4][2];

  for (int i = tid; i < 16*NN; i += 512){
    int m = i >> 9, t = i & (NN-1);
    ord_s[i] = orders[(size_t)(16*wg + m)*NN + t];
  }
  for (int i = tid; i < 16*(HID+8); i += 512)
    ((short*)hbuf[0])[i] = 0;

  s16x8 Bf[4][4];
  #pragma unroll
  for (int q = 0; q < 4; ++q)
    #pragma unroll
    for (int kt = 0; kt < 4; ++kt){
      int g = q*HID + w*16 + l15;
      const float* src = W_hh + (size_t)g*HID + kt*32 + l4*8;
      s16x8 v;
      #pragma unroll
      for (int e = 0; e < 8; ++e) v[e] = f2bf(src[e]);
      Bf[q][kt] = v;
    }
  __syncthreads();

  float c[4] = {0,0,0,0}, emb[4] = {0,0,0,0};
  float vA[4][4], vB[4][4];
  #pragma unroll
  for (int r = 0; r < 4; ++r){
    int ord = ord_s[(l4*4 + r)*NN];
    const float* base = IFW + (size_t)ord*(4*HID) + w*16 + l15;
    #pragma unroll
    for (int q = 0; q < 4; ++q) vA[q][r] = base[q*HID];
  }

  for (int t2 = 0; t2 < NN/2; ++t2){
    lstm_step(2*t2,     w, l15, l4, hbuf[0], hbuf[1], vA, vB, Bf, c, emb, ord_s, IFW);
    lstm_step(2*t2 + 1, w, l15, l4, hbuf[1], hbuf[0], vB, vA, Bf, c, emb, ord_s, IFW);
  }

  float* eL = (float*)&hbuf[0][0][0];
  #pragma unroll
  for (int r = 0; r < 4; ++r)
    eL[(l4*4 + r)*HID + w*16 + l15] = emb[r] * (1.0f/512.0f);
  __syncthreads();

  int hk = tid >> 7;
  int u  = tid & 127;
  float b1v = b1s[hk*HID + u];
  float w2v = W2s[hk*HID + u];
  const float* wcol = W1s + (size_t)hk*HID*HID + u;
  for (int m = 0; m < 16; ++m){
    const float4* es4 = (const float4*)(eL + m*HID);
    float pre = b1v;
    #pragma unroll 4
    for (int d4 = 0; d4 < 32; ++d4){
      float4 e4 = es4[d4];
      pre += e4.x * wcol[(4*d4+0)*HID];
      pre += e4.y * wcol[(4*d4+1)*HID];
      pre += e4.z * wcol[(4*d4+2)*HID];
      pre += e4.w * wcol[(4*d4+3)*HID];
    }
    float v = fmaxf(pre, 0.f) * w2v;
    #pragma unroll
    for (int off = 1; off < 64; off <<= 1) v += __shfl_xor(v, off);
    if (l == 0) part[hk][(tid >> 6) & 1] = v;
    __syncthreads();
    if (tid < 4) logits[tid*NN + 16*wg + m] = part[tid][0] + part[tid][1] + b2s[tid];
    __syncthreads();
  }
}

// ---------------- K3: BCE loss + softplus-weighted mixture ----------------
__global__ __launch_bounds__(512) void k_final(const float* __restrict__ logits,
                                               const int* __restrict__ label,
                                               const float* __restrict__ var_raw,
                                               float* __restrict__ out){
  int n = threadIdx.x;
  float lab = (float)label[0];
  float sp[4]; float tot = 0.f;
  #pragma unroll
  for (int k = 0; k < 4; ++k){ sp[k] = softplusf(var_raw[k]); tot += sp[k]; }
  float y = 0.f, bce = 0.f;
  #pragma unroll
  for (int k = 0; k < 4; ++k){
    float x = logits[k*NN + n];
    float yk = 1.0f / (1.0f + expf(-x));
    y += (sp[k] / tot) * yk;
    bce += lab * softplusf(-x) + (1.0f - lab) * softplusf(x);
  }
  out[1 + n] = y;
  __shared__ float pr[8];
  #pragma unroll
  for (int off = 1; off < 64; off <<= 1) bce += __shfl_xor(bce, off);
  if ((n & 63) == 0) pr[n >> 6] = bce;
  __syncthreads();
  if (n == 0){
    float ssum = 0.f;
    for (int i = 0; i < 8; ++i) ssum += pr[i];
    out[0] = ssum * (1.0f/512.0f);
  }
}

// ---------------- launcher ----------------
extern "C" void kernel_launch(void* const* d_in, const int* in_sizes, int n_in,
                              void* d_out, int out_size, void* d_ws, size_t ws_size,
                              hipStream_t stream) {
  const int*   node_tags = (const int*)  d_in[0];
  const float* adj       = (const float*)d_in[1];
  const int*   label     = (const int*)  d_in[2];
  const float* W_emb     = (const float*)d_in[3];
  const float* b_emb     = (const float*)d_in[4];
  const float* W_ih      = (const float*)d_in[5];
  const float* W_hh      = (const float*)d_in[6];
  const float* b_ih      = (const float*)d_in[7];
  const float* b_hh      = (const float*)d_in[8];
  const float* W1s       = (const float*)d_in[9];
  const float* b1s       = (const float*)d_in[10];
  const float* W2s       = (const float*)d_in[11];
  const float* b2s       = (const float*)d_in[12];
  const float* var_raw   = (const float*)d_in[13];
  float* out = (float*)d_out;

  float* ws     = (float*)d_ws;
  float* IFW    = ws + 65536;              // 512*512
  float* logits = IFW + 262144 + 65536;    // 4*512
  int*   orders = (int*)(logits + 2048);   // 512*512 int32

  k_mega1<<<dim3(NN/WPB + NN), dim3(64), 0, stream>>>(adj, orders, node_tags,
                                                      W_emb, b_emb, W_ih, b_ih,
                                                      b_hh, IFW);
  k_lstm <<<dim3(32),  dim3(512), 0, stream>>>(W_hh, IFW, orders, W1s, b1s,
                                               W2s, b2s, logits);
  k_final<<<dim3(1),   dim3(512), 0, stream>>>(logits, label, var_raw, out);
}

// Round 5
// 1126.679 us; speedup vs baseline: 2.2869x; 2.2869x over previous
//
#include <hip/hip_runtime.h>
#include <hip/hip_bf16.h>
#include <stdint.h>

#define NN 512
#define FEAT 128
#define EMBD 64
#define HID 128

typedef float f32x4 __attribute__((ext_vector_type(4)));
typedef short s16x8 __attribute__((ext_vector_type(8)));

// ---------------- Threefry-2x32 (exact JAX semantics) ----------------
__device__ __forceinline__ uint32_t rotl32(uint32_t v, int s){ return (v << s) | (v >> (32 - s)); }

__device__ __forceinline__ void tf2x32(uint32_t k0, uint32_t k1, uint32_t x0, uint32_t x1,
                                       uint32_t &o0, uint32_t &o1){
  uint32_t k2 = k0 ^ k1 ^ 0x1BD11BDAu;
  x0 += k0; x1 += k1;
  x0+=x1; x1=rotl32(x1,13); x1^=x0;
  x0+=x1; x1=rotl32(x1,15); x1^=x0;
  x0+=x1; x1=rotl32(x1,26); x1^=x0;
  x0+=x1; x1=rotl32(x1, 6); x1^=x0;
  x0 += k1; x1 += k2 + 1u;
  x0+=x1; x1=rotl32(x1,17); x1^=x0;
  x0+=x1; x1=rotl32(x1,29); x1^=x0;
  x0+=x1; x1=rotl32(x1,16); x1^=x0;
  x0+=x1; x1=rotl32(x1,24); x1^=x0;
  x0 += k2; x1 += k0 + 2u;
  x0+=x1; x1=rotl32(x1,13); x1^=x0;
  x0+=x1; x1=rotl32(x1,15); x1^=x0;
  x0+=x1; x1=rotl32(x1,26); x1^=x0;
  x0+=x1; x1=rotl32(x1, 6); x1^=x0;
  x0 += k0; x1 += k1 + 3u;
  x0+=x1; x1=rotl32(x1,17); x1^=x0;
  x0+=x1; x1=rotl32(x1,29); x1^=x0;
  x0+=x1; x1=rotl32(x1,16); x1^=x0;
  x0+=x1; x1=rotl32(x1,24); x1^=x0;
  x0 += k1; x1 += k2 + 4u;
  x0+=x1; x1=rotl32(x1,13); x1^=x0;
  x0+=x1; x1=rotl32(x1,15); x1^=x0;
  x0+=x1; x1=rotl32(x1,26); x1^=x0;
  x0+=x1; x1=rotl32(x1, 6); x1^=x0;
  x0 += k2; x1 += k0 + 5u;
  o0 = x0; o1 = x1;
}

// uniform(key,(n,),0.01,0.1) bit-exact elementwise transform
__device__ __forceinline__ float bits_to_noise(uint32_t bits){
  float u = __builtin_bit_cast(float, (bits >> 9) | 0x3f800000u) - 1.0f;
  const float dlt = 0.1f - 0.01f;
  float v = __fadd_rn(__fmul_rn(u, dlt), 0.01f); // no FMA, as XLA emits
  return fmaxf(0.01f, v);
}

__device__ __forceinline__ short f2bf(float f){
  uint32_t u = __builtin_bit_cast(uint32_t, f);
  u += 0x7fffu + ((u >> 16) & 1u);
  return (short)(u >> 16);
}

__device__ __forceinline__ float fsig(float x){
  return __builtin_amdgcn_rcpf(1.0f + __expf(-x));
}
__device__ __forceinline__ float ftanh(float x){
  float e = __expf(2.0f * x);
  return 1.0f - 2.0f * __builtin_amdgcn_rcpf(e + 1.0f);
}
__device__ __forceinline__ float softplusf(float x){
  return log1pf(expf(x));
}

// barrier that drains only LDS (lgkmcnt), letting global loads float across
__device__ __forceinline__ void lds_barrier(){
  asm volatile("s_waitcnt lgkmcnt(0)\n\ts_barrier" ::: "memory");
}

// ---------------- fast 64-lane reductions (DPP + swizzle) ----------------
__device__ __forceinline__ float wave_fmax(float x){
  int xi;
  #define DSTEP(C) xi = __builtin_amdgcn_update_dpp(0, __builtin_bit_cast(int,x), C, 0xF, 0xF, true); \
                   x = fmaxf(x, __builtin_bit_cast(float,xi));
  DSTEP(0xB1)   /* xor1  */
  DSTEP(0x4E)   /* xor2  */
  DSTEP(0x141)  /* xor4  row_half_mirror */
  DSTEP(0x140)  /* xor8  row_mirror      */
  #undef DSTEP
  xi = __builtin_amdgcn_ds_swizzle(__builtin_bit_cast(int,x), 0x401F); // xor16
  x = fmaxf(x, __builtin_bit_cast(float,xi));
  x = fmaxf(x, __shfl_xor(x, 32));
  return x;
}
__device__ __forceinline__ uint32_t wave_maxu(uint32_t x){
  int m;
  #define USTEP(C) m = __builtin_amdgcn_update_dpp(0, (int)x, C, 0xF, 0xF, true); \
                   x = x > (uint32_t)m ? x : (uint32_t)m;
  USTEP(0xB1) USTEP(0x4E) USTEP(0x141) USTEP(0x140)
  #undef USTEP
  m = __builtin_amdgcn_ds_swizzle((int)x, 0x401F);
  x = x > (uint32_t)m ? x : (uint32_t)m;
  uint32_t o = (uint32_t)__shfl_xor((int)x, 32);
  x = x > o ? x : o;
  return x;
}

// ---------------- mega-kernel body A: greedy noisy random-walk ----------------
// (exact round-3 code: bit-identical orders, known 537 us)
__device__ __forceinline__ void orders_body(const float* __restrict__ adj,
                                            int* __restrict__ orders, int s){
  int lane = threadIdx.x;
  __shared__ uint32_t kts[2*(NN-1)];
  __shared__ float ca[NN];
  __shared__ int   ci[NN];

  uint32_t ks0, ks1; tf2x32(0u, 42u, 0u, (uint32_t)s, ks0, ks1);
  for (int t = lane; t < NN-1; t += 64){
    uint32_t a, b; tf2x32(ks0, ks1, 0u, (uint32_t)t, a, b);
    kts[2*t] = a; kts[2*t+1] = b;
  }
  __syncthreads();

  uint32_t vis = 0;                       // bit e = visited(lane*8+e)
  if ((s >> 3) == lane) vis |= 1u << (s & 7);
  int cur = s;
  if (lane == 0) orders[(size_t)s*NN] = s;
  unsigned long long lt = (1ull << lane) - 1ull;

  for (int t = 0; t < NN-1; ++t){
    uint32_t kt0 = kts[2*t], kt1 = kts[2*t+1];
    const float4* r4 = (const float4*)(adj + (size_t)cur*NN);
    float4 v0 = r4[lane*2], v1 = r4[lane*2+1];
    float a[8] = {v0.x,v0.y,v0.z,v0.w,v1.x,v1.y,v1.z,v1.w};

    float mx = -1.f;
    #pragma unroll
    for (int e = 0; e < 8; ++e)
      mx = fmaxf(mx, ((vis >> e) & 1) ? -1.f : a[e]);
    mx = wave_fmax(mx);
    float T = mx - 0.0901f;

    int base = 0, pos[8]; uint32_t cm = 0;
    #pragma unroll
    for (int e = 0; e < 8; ++e){
      bool c = !((vis >> e) & 1) && (a[e] >= T);
      unsigned long long bal = __ballot(c);
      pos[e] = base + __popcll(bal & lt);
      base += __popcll(bal);
      if (c) cm |= 1u << e;
    }
    #pragma unroll
    for (int e = 0; e < 8; ++e)
      if ((cm >> e) & 1){ ca[pos[e]] = a[e]; ci[pos[e]] = lane*8 + e; }
    int total = base;

    uint32_t bk = 0; int bi = 0x7fffffff;
    for (int b0 = 0; b0 < total; b0 += 64){
      int k = b0 + lane;
      if (k < total){
        int idx = ci[k]; float av = ca[k];
        uint32_t x0, x1;
        tf2x32(kt0, kt1, 0u, (uint32_t)idx, x0, x1);
        float nz = bits_to_noise(x0 ^ x1);
        uint32_t a23 = (uint32_t)(av * 8388608.0f);      // *2^23 exact
        uint32_t n30 = (uint32_t)(nz * 1073741824.0f);   // *2^30 exact
        uint32_t key = (a23 << 7) + n30;
        if (key > bk || (key == bk && idx < bi)){ bk = key; bi = idx; }
      }
    }
    uint32_t km = wave_maxu(bk);
    unsigned long long msk = __ballot(bk == km);
    int widx;
    if (__popcll(msk) == 1){
      widx = __shfl(bi, __ffsll((long long)msk) - 1);
    } else {                                // rare exact-tie path
      int iv = (bk == km) ? bi : 0x7fffffff;
      #pragma unroll
      for (int off = 1; off < 64; off <<= 1){
        int o = __shfl_xor(iv, off);
        iv = o < iv ? o : iv;
      }
      widx = iv;
    }
    cur = widx;
    if ((widx >> 3) == lane) vis |= 1u << (widx & 7);
    if (lane == 0) orders[(size_t)s*NN + t + 1] = widx;
  }
}

// ---------------- mega-kernel body B: fused input_feat + IFW ----------------
// IFW stored gate-interleaved: IFW2[n][u][q] (u=hidden unit, q=gate i/f/g/o)
// so the LSTM gather is one float4 per (seq, unit).
__device__ __forceinline__ void featifw_body(int n, const int* __restrict__ tags,
    const float* __restrict__ adj, const float* __restrict__ W_emb,
    const float* __restrict__ b_emb, const float* __restrict__ W_ih,
    const float* __restrict__ b_ih, const float* __restrict__ b_hh,
    float* __restrict__ IFW){
  int tid = threadIdx.x;                 // = embedding dim d (0..63)
  __shared__ int tg[NN];
  __shared__ __align__(16) float xs[2*EMBD];
  for (int i = tid; i < NN; i += 64) tg[i] = tags[i];
  float nf = W_emb[tg[n]*EMBD + tid] + b_emb[tid];
  float ac = 0.f;
  for (int m = 0; m < NN; ++m){
    if (adj[(size_t)n*NN + m] > 0.5f) ac += W_emb[tg[m]*EMBD + tid];
  }
  xs[tid]        = nf;
  xs[EMBD + tid] = ac + b_emb[tid];
  __syncthreads();
  const float4* xs4 = (const float4*)xs;
  for (int it = 0; it < 8; ++it){
    int g = it*64 + tid;                 // gate-major index q*128+u
    const float4* wr4 = (const float4*)(W_ih + (size_t)g*(2*EMBD));
    float a2 = b_ih[g] + b_hh[g];
    #pragma unroll 8
    for (int kk = 0; kk < 32; ++kk){
      float4 wv = wr4[kk], xv = xs4[kk];
      a2 += wv.x*xv.x + wv.y*xv.y + wv.z*xv.z + wv.w*xv.w;
    }
    IFW[(size_t)n*(4*HID) + (g & 127)*4 + (g >> 7)] = a2;  // interleaved store
  }
}

__global__ __launch_bounds__(64) void k_mega1(const float* __restrict__ adj,
    int* __restrict__ orders, const int* __restrict__ tags,
    const float* __restrict__ W_emb, const float* __restrict__ b_emb,
    const float* __restrict__ W_ih, const float* __restrict__ b_ih,
    const float* __restrict__ b_hh, float* __restrict__ IFW){
  if (blockIdx.x < NN) orders_body(adj, orders, blockIdx.x);
  else                 featifw_body(blockIdx.x - NN, tags, adj, W_emb, b_emb,
                                    W_ih, b_ih, b_hh, IFW);
}

// ---------------- K2: persistent LSTM (8 waves) + fused MLP heads ----------------
__device__ __forceinline__ void lstm_step(int t, int w, int l15, int l4,
    const short (*hread)[HID+8], short (*hwrite)[HID+8],
    f32x4 (&vC)[4], f32x4 (&vN)[4],
    const s16x8 (&Bf)[4][4], float (&c)[4], float (&emb)[4],
    const int* ord_s, const float* __restrict__ IFW2){
  // prefetch next step's gather: one coalesced float4 per sequence
  int tn = (t + 1 < NN) ? t + 1 : NN - 1;
  #pragma unroll
  for (int r = 0; r < 4; ++r){
    int ord = ord_s[(l4*4 + r)*NN + tn];
    vN[r] = *(const f32x4*)(IFW2 + (size_t)ord*(4*HID) + (w*16 + l15)*4);
  }
  s16x8 Af[4];
  #pragma unroll
  for (int kt = 0; kt < 4; ++kt)
    Af[kt] = *(const s16x8*)&hread[l15][kt*32 + l4*8];
  f32x4 acc[4];
  #pragma unroll
  for (int q = 0; q < 4; ++q){
    f32x4 a = {vC[0][q], vC[1][q], vC[2][q], vC[3][q]};  // C-init = x@W_ih + b
    #pragma unroll
    for (int kt = 0; kt < 4; ++kt)
      a = __builtin_amdgcn_mfma_f32_16x16x32_bf16(Af[kt], Bf[q][kt], a, 0, 0, 0);
    acc[q] = a;
  }
  int col = w*16 + l15;
  #pragma unroll
  for (int r = 0; r < 4; ++r){
    float si = fsig(acc[0][r]);
    float sf = fsig(acc[1][r]);
    float tg = ftanh(acc[2][r]);
    float so = fsig(acc[3][r]);
    float cn = sf * c[r] + si * tg;
    c[r] = cn;
    float h = so * ftanh(cn);
    emb[r] += h;
    hwrite[l4*4 + r][col] = f2bf(h);
  }
  lds_barrier();   // drains LDS only; IFW prefetch stays in flight
}

__global__ __launch_bounds__(512, 2) void k_lstm(const float* __restrict__ W_hh,
    const float* __restrict__ IFW2, const int* __restrict__ orders,
    const float* __restrict__ W1s, const float* __restrict__ b1s,
    const float* __restrict__ W2s, const float* __restrict__ b2s,
    float* __restrict__ logits){
  int wg = blockIdx.x, tid = threadIdx.x;
  int w = tid >> 6, l = tid & 63, l15 = l & 15, l4 = l >> 4;
  __shared__ int ord_s[16*NN];
  __shared__ __align__(16) short hbuf[2][16][HID+8];
  __shared__ float part[4][2];

  for (int i = tid; i < 16*NN; i += 512){
    int m = i >> 9, t = i & (NN-1);
    ord_s[i] = orders[(size_t)(16*wg + m)*NN + t];
  }
  for (int i = tid; i < 16*(HID+8); i += 512)
    ((short*)hbuf[0])[i] = 0;

  s16x8 Bf[4][4];
  #pragma unroll
  for (int q = 0; q < 4; ++q)
    #pragma unroll
    for (int kt = 0; kt < 4; ++kt){
      int g = q*HID + w*16 + l15;
      const float* src = W_hh + (size_t)g*HID + kt*32 + l4*8;
      s16x8 v;
      #pragma unroll
      for (int e = 0; e < 8; ++e) v[e] = f2bf(src[e]);
      Bf[q][kt] = v;
    }
  __syncthreads();

  float c[4] = {0,0,0,0}, emb[4] = {0,0,0,0};
  f32x4 vA[4], vB[4];
  #pragma unroll
  for (int r = 0; r < 4; ++r){
    int ord = ord_s[(l4*4 + r)*NN];
    vA[r] = *(const f32x4*)(IFW2 + (size_t)ord*(4*HID) + (w*16 + l15)*4);
  }

  for (int t2 = 0; t2 < NN/2; ++t2){
    lstm_step(2*t2,     w, l15, l4, hbuf[0], hbuf[1], vA, vB, Bf, c, emb, ord_s, IFW2);
    lstm_step(2*t2 + 1, w, l15, l4, hbuf[1], hbuf[0], vB, vA, Bf, c, emb, ord_s, IFW2);
  }

  float* eL = (float*)&hbuf[0][0][0];
  #pragma unroll
  for (int r = 0; r < 4; ++r)
    eL[(l4*4 + r)*HID + w*16 + l15] = emb[r] * (1.0f/512.0f);
  __syncthreads();

  int hk = tid >> 7;
  int u  = tid & 127;
  float b1v = b1s[hk*HID + u];
  float w2v = W2s[hk*HID + u];
  const float* wcol = W1s + (size_t)hk*HID*HID + u;
  for (int m = 0; m < 16; ++m){
    const float4* es4 = (const float4*)(eL + m*HID);
    float pre = b1v;
    #pragma unroll 4
    for (int d4 = 0; d4 < 32; ++d4){
      float4 e4 = es4[d4];
      pre += e4.x * wcol[(4*d4+0)*HID];
      pre += e4.y * wcol[(4*d4+1)*HID];
      pre += e4.z * wcol[(4*d4+2)*HID];
      pre += e4.w * wcol[(4*d4+3)*HID];
    }
    float v = fmaxf(pre, 0.f) * w2v;
    #pragma unroll
    for (int off = 1; off < 64; off <<= 1) v += __shfl_xor(v, off);
    if (l == 0) part[hk][(tid >> 6) & 1] = v;
    __syncthreads();
    if (tid < 4) logits[tid*NN + 16*wg + m] = part[tid][0] + part[tid][1] + b2s[tid];
    __syncthreads();
  }
}

// ---------------- K3: BCE loss + softplus-weighted mixture ----------------
__global__ __launch_bounds__(512) void k_final(const float* __restrict__ logits,
                                               const int* __restrict__ label,
                                               const float* __restrict__ var_raw,
                                               float* __restrict__ out){
  int n = threadIdx.x;
  float lab = (float)label[0];
  float sp[4]; float tot = 0.f;
  #pragma unroll
  for (int k = 0; k < 4; ++k){ sp[k] = softplusf(var_raw[k]); tot += sp[k]; }
  float y = 0.f, bce = 0.f;
  #pragma unroll
  for (int k = 0; k < 4; ++k){
    float x = logits[k*NN + n];
    float yk = 1.0f / (1.0f + expf(-x));
    y += (sp[k] / tot) * yk;
    bce += lab * softplusf(-x) + (1.0f - lab) * softplusf(x);
  }
  out[1 + n] = y;
  __shared__ float pr[8];
  #pragma unroll
  for (int off = 1; off < 64; off <<= 1) bce += __shfl_xor(bce, off);
  if ((n & 63) == 0) pr[n >> 6] = bce;
  __syncthreads();
  if (n == 0){
    float ssum = 0.f;
    for (int i = 0; i < 8; ++i) ssum += pr[i];
    out[0] = ssum * (1.0f/512.0f);
  }
}

// ---------------- launcher ----------------
extern "C" void kernel_launch(void* const* d_in, const int* in_sizes, int n_in,
                              void* d_out, int out_size, void* d_ws, size_t ws_size,
                              hipStream_t stream) {
  const int*   node_tags = (const int*)  d_in[0];
  const float* adj       = (const float*)d_in[1];
  const int*   label     = (const int*)  d_in[2];
  const float* W_emb     = (const float*)d_in[3];
  const float* b_emb     = (const float*)d_in[4];
  const float* W_ih      = (const float*)d_in[5];
  const float* W_hh      = (const float*)d_in[6];
  const float* b_ih      = (const float*)d_in[7];
  const float* b_hh      = (const float*)d_in[8];
  const float* W1s       = (const float*)d_in[9];
  const float* b1s       = (const float*)d_in[10];
  const float* W2s       = (const float*)d_in[11];
  const float* b2s       = (const float*)d_in[12];
  const float* var_raw   = (const float*)d_in[13];
  float* out = (float*)d_out;

  float* ws     = (float*)d_ws;
  float* IFW    = ws + 65536;              // 512*512 (gate-interleaved)
  float* logits = IFW + 262144 + 65536;    // 4*512
  int*   orders = (int*)(logits + 2048);   // 512*512 int32

  k_mega1<<<dim3(2*NN), dim3(64), 0, stream>>>(adj, orders, node_tags, W_emb,
                                               b_emb, W_ih, b_ih, b_hh, IFW);
  k_lstm <<<dim3(32),  dim3(512), 0, stream>>>(W_hh, IFW, orders, W1s, b1s,
                                               W2s, b2s, logits);
  k_final<<<dim3(1),   dim3(512), 0, stream>>>(logits, label, var_raw, out);
}

// Round 6
// 1102.635 us; speedup vs baseline: 2.3367x; 1.0218x over previous
//
#include <hip/hip_runtime.h>
#include <hip/hip_bf16.h>
#include <stdint.h>

#define NN 512
#define FEAT 128
#define EMBD 64
#define HID 128

typedef float f32x4 __attribute__((ext_vector_type(4)));
typedef short s16x8 __attribute__((ext_vector_type(8)));

// ---------------- Threefry-2x32 (exact JAX semantics) ----------------
__device__ __forceinline__ uint32_t rotl32(uint32_t v, int s){ return (v << s) | (v >> (32 - s)); }

__device__ __forceinline__ void tf2x32(uint32_t k0, uint32_t k1, uint32_t x0, uint32_t x1,
                                       uint32_t &o0, uint32_t &o1){
  uint32_t k2 = k0 ^ k1 ^ 0x1BD11BDAu;
  x0 += k0; x1 += k1;
  x0+=x1; x1=rotl32(x1,13); x1^=x0;
  x0+=x1; x1=rotl32(x1,15); x1^=x0;
  x0+=x1; x1=rotl32(x1,26); x1^=x0;
  x0+=x1; x1=rotl32(x1, 6); x1^=x0;
  x0 += k1; x1 += k2 + 1u;
  x0+=x1; x1=rotl32(x1,17); x1^=x0;
  x0+=x1; x1=rotl32(x1,29); x1^=x0;
  x0+=x1; x1=rotl32(x1,16); x1^=x0;
  x0+=x1; x1=rotl32(x1,24); x1^=x0;
  x0 += k2; x1 += k0 + 2u;
  x0+=x1; x1=rotl32(x1,13); x1^=x0;
  x0+=x1; x1=rotl32(x1,15); x1^=x0;
  x0+=x1; x1=rotl32(x1,26); x1^=x0;
  x0+=x1; x1=rotl32(x1, 6); x1^=x0;
  x0 += k0; x1 += k1 + 3u;
  x0+=x1; x1=rotl32(x1,17); x1^=x0;
  x0+=x1; x1=rotl32(x1,29); x1^=x0;
  x0+=x1; x1=rotl32(x1,16); x1^=x0;
  x0+=x1; x1=rotl32(x1,24); x1^=x0;
  x0 += k1; x1 += k2 + 4u;
  x0+=x1; x1=rotl32(x1,13); x1^=x0;
  x0+=x1; x1=rotl32(x1,15); x1^=x0;
  x0+=x1; x1=rotl32(x1,26); x1^=x0;
  x0+=x1; x1=rotl32(x1, 6); x1^=x0;
  x0 += k2; x1 += k0 + 5u;
  o0 = x0; o1 = x1;
}

// uniform(key,(n,),0.01,0.1) bit-exact elementwise transform
__device__ __forceinline__ float bits_to_noise(uint32_t bits){
  float u = __builtin_bit_cast(float, (bits >> 9) | 0x3f800000u) - 1.0f;
  const float dlt = 0.1f - 0.01f;
  float v = __fadd_rn(__fmul_rn(u, dlt), 0.01f); // no FMA, as XLA emits
  return fmaxf(0.01f, v);
}

__device__ __forceinline__ short f2bf(float f){
  uint32_t u = __builtin_bit_cast(uint32_t, f);
  u += 0x7fffu + ((u >> 16) & 1u);
  return (short)(u >> 16);
}

__device__ __forceinline__ float fsig(float x){
  return __builtin_amdgcn_rcpf(1.0f + __expf(-x));
}
__device__ __forceinline__ float ftanh(float x){
  float e = __expf(2.0f * x);
  return 1.0f - 2.0f * __builtin_amdgcn_rcpf(e + 1.0f);
}
__device__ __forceinline__ float softplusf(float x){
  return log1pf(expf(x));
}

// barrier that drains only LDS (lgkmcnt), letting global loads float across
__device__ __forceinline__ void lds_barrier(){
  asm volatile("s_waitcnt lgkmcnt(0)\n\ts_barrier" ::: "memory");
}

// ---------------- fast 64-lane reductions (DPP + swizzle) ----------------
__device__ __forceinline__ float wave_fmax(float x){
  int xi;
  #define DSTEP(C) xi = __builtin_amdgcn_update_dpp(0, __builtin_bit_cast(int,x), C, 0xF, 0xF, true); \
                   x = fmaxf(x, __builtin_bit_cast(float,xi));
  DSTEP(0xB1)   /* xor1  */
  DSTEP(0x4E)   /* xor2  */
  DSTEP(0x141)  /* xor4  row_half_mirror */
  DSTEP(0x140)  /* xor8  row_mirror      */
  #undef DSTEP
  xi = __builtin_amdgcn_ds_swizzle(__builtin_bit_cast(int,x), 0x401F); // xor16
  x = fmaxf(x, __builtin_bit_cast(float,xi));
  x = fmaxf(x, __shfl_xor(x, 32));
  return x;
}
__device__ __forceinline__ uint32_t wave_maxu(uint32_t x){
  int m;
  #define USTEP(C) m = __builtin_amdgcn_update_dpp(0, (int)x, C, 0xF, 0xF, true); \
                   x = x > (uint32_t)m ? x : (uint32_t)m;
  USTEP(0xB1) USTEP(0x4E) USTEP(0x141) USTEP(0x140)
  #undef USTEP
  m = __builtin_amdgcn_ds_swizzle((int)x, 0x401F);
  x = x > (uint32_t)m ? x : (uint32_t)m;
  uint32_t o = (uint32_t)__shfl_xor((int)x, 32);
  x = x > o ? x : o;
  return x;
}

// ---------------- mega-kernel body A: greedy noisy random-walk ----------------
// Same selection math as round 3 (bit-identical orders).  Changes: candidate
// array packed to one u32 (a23<<9)|idx (one ds_read on the chain), and the
// next row load issues the moment the winner is known.
__device__ __forceinline__ void orders_body(const float* __restrict__ adj,
                                            int* __restrict__ orders, int s){
  int lane = threadIdx.x;
  __shared__ uint32_t kts[2*(NN-1)];
  __shared__ uint32_t pcs[NN];

  uint32_t ks0, ks1; tf2x32(0u, 42u, 0u, (uint32_t)s, ks0, ks1);
  for (int t = lane; t < NN-1; t += 64){
    uint32_t a, b; tf2x32(ks0, ks1, 0u, (uint32_t)t, a, b);
    kts[2*t] = a; kts[2*t+1] = b;
  }
  __syncthreads();

  uint32_t vis = 0;                       // bit e = visited(lane*8+e)
  if ((s >> 3) == lane) vis |= 1u << (s & 7);
  if (lane == 0) orders[(size_t)s*NN] = s;
  unsigned long long lt = (1ull << lane) - 1ull;

  const float4* r4 = (const float4*)(adj + (size_t)s*NN);
  float4 v0 = r4[lane*2], v1 = r4[lane*2+1];

  for (int t = 0; t < NN-1; ++t){
    uint32_t kt0 = kts[2*t], kt1 = kts[2*t+1];
    float a[8] = {v0.x,v0.y,v0.z,v0.w,v1.x,v1.y,v1.z,v1.w};

    float mx = -1.f;
    #pragma unroll
    for (int e = 0; e < 8; ++e)
      mx = fmaxf(mx, ((vis >> e) & 1) ? -1.f : a[e]);
    mx = wave_fmax(mx);
    float T = mx - 0.0901f;

    int base = 0, pos[8]; uint32_t cm = 0;
    #pragma unroll
    for (int e = 0; e < 8; ++e){
      bool c = !((vis >> e) & 1) && (a[e] >= T);
      unsigned long long bal = __ballot(c);
      pos[e] = base + __popcll(bal & lt);
      base += __popcll(bal);
      if (c) cm |= 1u << e;
    }
    #pragma unroll
    for (int e = 0; e < 8; ++e)
      if ((cm >> e) & 1){
        uint32_t a23 = (uint32_t)(a[e] * 8388608.0f);       // *2^23 exact
        pcs[pos[e]] = (a23 << 9) | (uint32_t)(lane*8 + e);
      }
    int total = base;

    uint32_t bk = 0; int bi = 0x7fffffff;
    for (int b0 = 0; b0 < total; b0 += 64){
      int k = b0 + lane;
      if (k < total){
        uint32_t pc = pcs[k];
        int idx = (int)(pc & 511u);
        uint32_t x0, x1;
        tf2x32(kt0, kt1, 0u, (uint32_t)idx, x0, x1);
        float nz = bits_to_noise(x0 ^ x1);
        uint32_t n30 = (uint32_t)(nz * 1073741824.0f);      // *2^30 exact
        uint32_t key = ((pc >> 9) << 7) + n30;
        if (key > bk || (key == bk && idx < bi)){ bk = key; bi = idx; }
      }
    }
    uint32_t km = wave_maxu(bk);
    unsigned long long msk = __ballot(bk == km);
    int widx;
    if (__popcll(msk) == 1){
      widx = __shfl(bi, __ffsll((long long)msk) - 1);
    } else {                                // rare exact-tie path
      int iv = (bk == km) ? bi : 0x7fffffff;
      #pragma unroll
      for (int off = 1; off < 64; off <<= 1){
        int o = __shfl_xor(iv, off);
        iv = o < iv ? o : iv;
      }
      widx = iv;
    }
    // issue next row load immediately; everything after is off the load path
    const float4* nr = (const float4*)(adj + (size_t)widx*NN);
    v0 = nr[lane*2]; v1 = nr[lane*2+1];
    if ((widx >> 3) == lane) vis |= 1u << (widx & 7);
    if (lane == 0) orders[(size_t)s*NN + t + 1] = widx;
  }
}

// ---------------- mega-kernel body B: fused input_feat + IFW ----------------
// IFW stored gate-interleaved: IFW2[n][u][q] (u=hidden unit, q=gate i/f/g/o)
__device__ __forceinline__ void featifw_body(int n, const int* __restrict__ tags,
    const float* __restrict__ adj, const float* __restrict__ W_emb,
    const float* __restrict__ b_emb, const float* __restrict__ W_ih,
    const float* __restrict__ b_ih, const float* __restrict__ b_hh,
    float* __restrict__ IFW){
  int tid = threadIdx.x;                 // = embedding dim d (0..63)
  __shared__ int tg[NN];
  __shared__ __align__(16) float xs[2*EMBD];
  for (int i = tid; i < NN; i += 64) tg[i] = tags[i];
  float nf = W_emb[tg[n]*EMBD + tid] + b_emb[tid];
  float ac = 0.f;
  for (int m = 0; m < NN; ++m){
    if (adj[(size_t)n*NN + m] > 0.5f) ac += W_emb[tg[m]*EMBD + tid];
  }
  xs[tid]        = nf;
  xs[EMBD + tid] = ac + b_emb[tid];
  __syncthreads();
  const float4* xs4 = (const float4*)xs;
  for (int it = 0; it < 8; ++it){
    int g = it*64 + tid;                 // gate-major index q*128+u
    const float4* wr4 = (const float4*)(W_ih + (size_t)g*(2*EMBD));
    float a2 = b_ih[g] + b_hh[g];
    #pragma unroll 8
    for (int kk = 0; kk < 32; ++kk){
      float4 wv = wr4[kk], xv = xs4[kk];
      a2 += wv.x*xv.x + wv.y*xv.y + wv.z*xv.z + wv.w*xv.w;
    }
    IFW[(size_t)n*(4*HID) + (g & 127)*4 + (g >> 7)] = a2;  // interleaved store
  }
}

__global__ __launch_bounds__(64) void k_mega1(const float* __restrict__ adj,
    int* __restrict__ orders, const int* __restrict__ tags,
    const float* __restrict__ W_emb, const float* __restrict__ b_emb,
    const float* __restrict__ W_ih, const float* __restrict__ b_ih,
    const float* __restrict__ b_hh, float* __restrict__ IFW){
  if (blockIdx.x < NN) orders_body(adj, orders, blockIdx.x);
  else                 featifw_body(blockIdx.x - NN, tags, adj, W_emb, b_emb,
                                    W_ih, b_ih, b_hh, IFW);
}

// ---------------- K2: LSTM, 128 blocks x 4 seqs, LDS-redistributed epilogue ----
// MFMA phase: 8 waves x 16 units, A rows 0-3 live (12 dead rows cost nothing:
// MfmaUtil ~0).  Gates for (seq r, unit u) land in lanes l4==0; written to LDS.
// Epilogue phase: 512 threads each compute exactly ONE h (seq em, unit eu) ->
// per-wave transcendental issue drops 4x and the grid covers 128 CUs not 32.
__global__ __launch_bounds__(512, 2) void k_lstm(const float* __restrict__ W_hh,
    const float* __restrict__ IFW2, const int* __restrict__ orders,
    const float* __restrict__ W1s, const float* __restrict__ b1s,
    const float* __restrict__ W2s, const float* __restrict__ b2s,
    float* __restrict__ logits){
  int wg = blockIdx.x, tid = threadIdx.x;       // seqs 4*wg .. 4*wg+3
  int w = tid >> 6, l = tid & 63, l15 = l & 15, l4 = l >> 4;
  int em = tid >> 7, eu = tid & 127;            // epilogue (seq, unit)

  __shared__ int ord_s[4*NN];                       // 8 KB
  __shared__ __align__(16) short hbuf[16][HID+8];   // 4.25 KB (rows 4-15 stay 0)
  __shared__ __align__(16) float gl[4][520];        // 8.3 KB gates [r][u*4+q]
  __shared__ float part[4][2];

  for (int i = tid; i < 4*NN; i += 512)
    ord_s[i] = orders[(size_t)(4*wg)*NN + i];       // ord_s[m*NN + t]
  for (int i = tid; i < 16*(HID+8); i += 512)
    ((short*)hbuf)[i] = 0;

  // W_hh -> bf16 B-fragments in registers; wave w owns units w*16..w*16+15
  s16x8 Bf[4][4];
  #pragma unroll
  for (int q = 0; q < 4; ++q)
    #pragma unroll
    for (int kt = 0; kt < 4; ++kt){
      int g = q*HID + w*16 + l15;
      const float* src = W_hh + (size_t)g*HID + kt*32 + l4*8;
      s16x8 v;
      #pragma unroll
      for (int e = 0; e < 8; ++e) v[e] = f2bf(src[e]);
      Bf[q][kt] = v;
    }
  __syncthreads();

  int u = w*16 + l15;
  float cst = 0.f, emb = 0.f;                   // c, sum(h) for (em, eu)

  f32x4 vif[4];                                 // IFW gates rows 0-3 (l4==0 only)
  if (l4 == 0){
    #pragma unroll
    for (int r = 0; r < 4; ++r)
      vif[r] = *(const f32x4*)(IFW2 + (size_t)ord_s[r*NN]*(4*HID) + u*4);
  }

  for (int t = 0; t < NN; ++t){
    s16x8 Af[4];
    #pragma unroll
    for (int kt = 0; kt < 4; ++kt)
      Af[kt] = *(const s16x8*)&hbuf[l15][kt*32 + l4*8];

    f32x4 acc[4];
    #pragma unroll
    for (int q = 0; q < 4; ++q){
      f32x4 a = {0.f, 0.f, 0.f, 0.f};
      #pragma unroll
      for (int kt = 0; kt < 4; ++kt)
        a = __builtin_amdgcn_mfma_f32_16x16x32_bf16(Af[kt], Bf[q][kt], a, 0, 0, 0);
      acc[q] = a;
    }

    // prefetch next step's IFW gates (in flight across both barriers)
    int tn = (t + 1 < NN) ? t + 1 : NN - 1;
    f32x4 vifn[4];
    if (l4 == 0){
      #pragma unroll
      for (int r = 0; r < 4; ++r)
        vifn[r] = *(const f32x4*)(IFW2 + (size_t)ord_s[r*NN + tn]*(4*HID) + u*4);
      // write gates for this step
      #pragma unroll
      for (int q = 0; q < 4; ++q)
        #pragma unroll
        for (int r = 0; r < 4; ++r)
          gl[r][u*4 + q] = acc[q][r] + vif[r][q];
    }
    lds_barrier();

    // epilogue: one h per thread
    f32x4 g4 = *(const f32x4*)&gl[em][eu*4];
    float si = fsig(g4[0]);
    float sf = fsig(g4[1]);
    float tg = ftanh(g4[2]);
    float so = fsig(g4[3]);
    float cn = sf * cst + si * tg;
    cst = cn;
    float h = so * ftanh(cn);
    emb += h;
    hbuf[em][eu] = f2bf(h);
    #pragma unroll
    for (int r = 0; r < 4; ++r) vif[r] = vifn[r];
    lds_barrier();
  }

  // ---- fused MLP heads over this block's 4 nodes ----
  float* eL = (float*)gl;                       // [4][HID] view
  eL[em*HID + eu] = emb * (1.0f/512.0f);
  __syncthreads();

  int hk = tid >> 7;          // head 0..3
  int uu = tid & 127;         // hidden unit
  float b1v = b1s[hk*HID + uu];
  float w2v = W2s[hk*HID + uu];
  const float* wcol = W1s + (size_t)hk*HID*HID + uu;
  for (int m = 0; m < 4; ++m){
    const float4* es4 = (const float4*)(eL + m*HID);
    float pre = b1v;
    #pragma unroll 4
    for (int d4 = 0; d4 < 32; ++d4){
      float4 e4 = es4[d4];
      pre += e4.x * wcol[(4*d4+0)*HID];
      pre += e4.y * wcol[(4*d4+1)*HID];
      pre += e4.z * wcol[(4*d4+2)*HID];
      pre += e4.w * wcol[(4*d4+3)*HID];
    }
    float v = fmaxf(pre, 0.f) * w2v;
    #pragma unroll
    for (int off = 1; off < 64; off <<= 1) v += __shfl_xor(v, off);
    if (l == 0) part[hk][(tid >> 6) & 1] = v;
    __syncthreads();
    if (tid < 4) logits[tid*NN + 4*wg + m] = part[tid][0] + part[tid][1] + b2s[tid];
    __syncthreads();
  }
}

// ---------------- K3: BCE loss + softplus-weighted mixture ----------------
__global__ __launch_bounds__(512) void k_final(const float* __restrict__ logits,
                                               const int* __restrict__ label,
                                               const float* __restrict__ var_raw,
                                               float* __restrict__ out){
  int n = threadIdx.x;
  float lab = (float)label[0];
  float sp[4]; float tot = 0.f;
  #pragma unroll
  for (int k = 0; k < 4; ++k){ sp[k] = softplusf(var_raw[k]); tot += sp[k]; }
  float y = 0.f, bce = 0.f;
  #pragma unroll
  for (int k = 0; k < 4; ++k){
    float x = logits[k*NN + n];
    float yk = 1.0f / (1.0f + expf(-x));
    y += (sp[k] / tot) * yk;
    bce += lab * softplusf(-x) + (1.0f - lab) * softplusf(x);
  }
  out[1 + n] = y;
  __shared__ float pr[8];
  #pragma unroll
  for (int off = 1; off < 64; off <<= 1) bce += __shfl_xor(bce, off);
  if ((n & 63) == 0) pr[n >> 6] = bce;
  __syncthreads();
  if (n == 0){
    float ssum = 0.f;
    for (int i = 0; i < 8; ++i) ssum += pr[i];
    out[0] = ssum * (1.0f/512.0f);
  }
}

// ---------------- launcher ----------------
extern "C" void kernel_launch(void* const* d_in, const int* in_sizes, int n_in,
                              void* d_out, int out_size, void* d_ws, size_t ws_size,
                              hipStream_t stream) {
  const int*   node_tags = (const int*)  d_in[0];
  const float* adj       = (const float*)d_in[1];
  const int*   label     = (const int*)  d_in[2];
  const float* W_emb     = (const float*)d_in[3];
  const float* b_emb     = (const float*)d_in[4];
  const float* W_ih      = (const float*)d_in[5];
  const float* W_hh      = (const float*)d_in[6];
  const float* b_ih      = (const float*)d_in[7];
  const float* b_hh      = (const float*)d_in[8];
  const float* W1s       = (const float*)d_in[9];
  const float* b1s       = (const float*)d_in[10];
  const float* W2s       = (const float*)d_in[11];
  const float* b2s       = (const float*)d_in[12];
  const float* var_raw   = (const float*)d_in[13];
  float* out = (float*)d_out;

  float* ws     = (float*)d_ws;
  float* IFW    = ws + 65536;              // 512*512 (gate-interleaved)
  float* logits = IFW + 262144 + 65536;    // 4*512
  int*   orders = (int*)(logits + 2048);   // 512*512 int32

  k_mega1<<<dim3(2*NN), dim3(64), 0, stream>>>(adj, orders, node_tags, W_emb,
                                               b_emb, W_ih, b_ih, b_hh, IFW);
  k_lstm <<<dim3(128), dim3(512), 0, stream>>>(W_hh, IFW, orders, W1s, b1s,
                                               W2s, b2s, logits);
  k_final<<<dim3(1),   dim3(512), 0, stream>>>(logits, label, var_raw, out);
}